// Round 17
// baseline (1678.024 us; speedup 1.0000x reference)
//
#include <hip/hip_runtime.h>
#include <math.h>

// Problem constants: N=200 LSTMs, B=100, T=256, D=5 (io), H=20 (units)
constexpr int NL = 200;
constexpr int B  = 100;
constexpr int T  = 256;
constexpr int D  = 5;
constexpr int H  = 20;
constexpr int NW = 7;       // 16-batch groups per LSTM; 7*16=112 >= 100
constexpr int KP = 40;      // bcol row pitch in bf16 (80 B)
constexpr int NWAVE = 5;    // wave m computes recurrence tile Mt=m
constexpr int BLKT  = 64 * NWAVE;   // 320 threads
constexpr int BPAD  = 112;  // padded batch dim of xe

// k-axis layout of the per-batch data column (K=32):
//   k 0..23  = h region, k = g*6 + mt  (hh = mt*4 + g; mt==5 -> always 0)
//   k 24..28 = x_t[0..4]  (one int4 = 16B store per step, k24..31, via xpack)
//   k 30     = 1.0 (bias slot, baked into xpack), k 29,31 = 0
constexpr int KX = 24;

typedef float  f32x4  __attribute__((ext_vector_type(4)));
typedef short  bf16x8 __attribute__((ext_vector_type(8)));

__device__ __forceinline__ float rcpf(float x) { return __builtin_amdgcn_rcpf(x); }

#if __has_builtin(__builtin_amdgcn_exp2f)
__device__ __forceinline__ float exp2fast(float x) { return __builtin_amdgcn_exp2f(x); }
#else
__device__ __forceinline__ float exp2fast(float x) { return __expf(x * 0.6931471805599453f); }
#endif

// fp32 -> bf16 bits, round-to-nearest-even
__device__ __forceinline__ unsigned short f2bf(float f) {
    union { float f; unsigned u; } v; v.f = f;
    unsigned r = v.u + 0x7fffu + ((v.u >> 16) & 1u);
    return (unsigned short)(r >> 16);
}
__device__ __forceinline__ unsigned pk2bf(float lo, float hi) {
    return (unsigned)f2bf(lo) | ((unsigned)f2bf(hi) << 16);
}

// LDS-only block barrier: global atomics (dense) and loads (x prefetch)
// stay in flight across steps (no vmcnt drain).
__device__ __forceinline__ void block_sync_lds() {
    asm volatile("s_waitcnt lgkmcnt(0)" ::: "memory");
    __builtin_amdgcn_s_barrier();
}

constexpr float NLOG2E = -1.4426950408889634f;
constexpr float TLOG2E = 2.8853900817779268f;   // 2*log2(e)

__global__ __launch_bounds__(256) void init_out_kernel(const float* __restrict__ dense_b,
                                                       float* __restrict__ out, int n) {
    int i = blockIdx.x * 256 + threadIdx.x;
    if (i < n) out[i] = dense_b[i % D];
}

// xe[t][b] = int4 B-fragment piece for k=24..31:
//   {pk(x0,x1), pk(x2,x3), pk(x4,0), pk(1.0,0)}  ([t][b] order -> 16
//   consecutive-b lanes read 256B = 2 cache lines)
__global__ __launch_bounds__(256) void xpack_kernel(const float* __restrict__ x,
                                                    int4* __restrict__ xe) {
    int i = blockIdx.x * 256 + threadIdx.x;   // i = t*BPAD + b
    if (i >= T * BPAD) return;
    const int t = i / BPAD;
    const int b = i % BPAD;
    int4 v = {0, 0, 0, 0};
    if (b < B) {
        const float* s = x + ((size_t)b * T + t) * D;
        v.x = (int)pk2bf(s[0], s[1]);
        v.y = (int)pk2bf(s[2], s[3]);
        v.z = (int)pk2bf(s[4], 0.0f);
        v.w = 0x00003F80;                     // (bf16 1.0, 0) -> k30 bias
    }
    xe[i] = v;
}

// One block per (lstm n, 16-batch group w); 5 waves per block (R10 structure,
// best measured). Wave m: ONE gate-tile MFMA + ONE activation chain per step;
// lane (c16,g4) owns (hh = 4m+g4, b = 16w+c16), writes ONE bf16 h. Wave 1
// extra: dense MFMA, pipelined one step behind, accumulated DIRECTLY into out
// via fire-and-forget atomicAdd (no pw workspace, no reduce pass). Wave 0
// lanes<16 extra: stage the pre-packed x int4 into the other buffer.
// bcol double-buffered; ONE lgkm-only barrier per step.
__global__ __attribute__((amdgpu_flat_work_group_size(BLKT, BLKT)))
void lstm_mfma5_kernel(
    const int4*  __restrict__ xe,   // [T][BPAD] packed x fragments
    const float* __restrict__ Wg,   // [N][D][4H]
    const float* __restrict__ Ug,   // [N][H][4H]
    const float* __restrict__ bg,   // [N][4H]
    const float* __restrict__ dWg,  // [N*H][D]
    float* __restrict__ out)        // [B][T][D], pre-initialized with dense_b
{
    const int blk = blockIdx.x;            // 0..1399
    const int n   = blk / NW;
    const int w   = blk % NW;
    const int tid = threadIdx.x;
    const int wid = tid >> 6;              // 0..4 = Mt of this wave
    const int l   = tid & 63;
    const int c16 = l & 15;
    const int g4  = l >> 4;

    __shared__ __align__(16) short bcol[2][16][KP];   // double-buffered

    for (int i = tid; i < 2 * 16 * KP / 2; i += BLKT)
        ((int*)&bcol[0][0][0])[i] = 0;

    const float* Un = Ug  + (size_t)n * H * 4 * H;
    const float* Wn = Wg  + (size_t)n * D * 4 * H;
    const float* bn = bg  + (size_t)n * 4 * H;
    const float* dn = dWg + (size_t)n * H * D;

    // ---- recurrence A fragment for this wave (Mt = wid), k = 8*g4 + j ----
    const int gateA = c16 & 3;
    const int hA4   = c16 >> 2;
    const float sA  = (gateA == 2) ? TLOG2E : NLOG2E;
    const int colA  = gateA * H + (wid * 4 + hA4);   // column in [*,4H] weights
    bf16x8 afrag;
    #pragma unroll
    for (int j = 0; j < 8; ++j) {
        const int k = 8 * g4 + j;
        float v = 0.0f;
        if (k < KX) {                          // h region: k = g*6 + mt
            const int mt = k % 6, gg = k / 6;
            if (mt < 5) v = Un[(mt * 4 + gg) * 4 * H + colA];
        } else if (k < KX + D) {               // x region
            v = Wn[(k - KX) * 4 * H + colA];
        } else if (k == 30) {                  // bias slot
            v = bn[colA];
        }
        afrag[j] = (short)f2bf(sA * v);
    }
    // ---- dense A fragment (wave 1 only): rows 0..4 = d, h region only ----
    bf16x8 afrag_d = {};
    if (wid == 1) {
        #pragma unroll
        for (int j = 0; j < 8; ++j) {
            const int k = 8 * g4 + j;
            float v = 0.0f;
            if (c16 < D && k < KX) {
                const int mt = k % 6, gg = k / 6;
                if (mt < 5) v = dn[(mt * 4 + gg) * D + c16];
            }
            afrag_d[j] = (short)f2bf(v);
        }
    }

    const int  bgl    = w * 16 + c16;          // global batch of this lane-col
    const bool bvalid = bgl < B;
    const int4* xq = xe + bgl;                 // row stride BPAD
    float* ob = out + (size_t)(bvalid ? bgl : 0) * T * D;

    __syncthreads();                            // zero-init visible

    // prologue: wave0 stages x(0) into buf 0; preloads x(1)
    int4 xn4;
    if (wid == 0 && l < 16) {
        *(int4*)&bcol[0][c16][KX] = xq[0];
        xn4 = xq[(T > 1 ? 1 : 0) * BPAD];
    }
    __syncthreads();

    float cst = 0.0f;
    const f32x4 zero4 = {0.0f, 0.0f, 0.0f, 0.0f};
    int p = 0;

    for (int t = 0; t < T; ++t) {
        // buf[p] holds h(t-1) and x(t)
        const bf16x8 bfrag = *(const bf16x8*)&bcol[p][c16][8 * g4];  // ds_read_b128

        if (wid == 1) {
            // dense for step t-1 (uses h(t-1) in bfrag); accumulate into out.
            // Fire-and-forget atomics: 200 n-writers per address, spread over
            // the kernel's lifetime by natural block drift (not lockstep).
            const f32x4 accd = __builtin_amdgcn_mfma_f32_16x16x32_bf16(
                afrag_d, bfrag, zero4, 0, 0, 0);
            if (t > 0 && bvalid) {
                float* pt = ob + (size_t)(t - 1) * D;
                #pragma unroll
                for (int reg = 0; reg < 4; ++reg) {
                    const int d = g4 * 4 + reg;            // output row = d
                    if (d < D) atomicAdd(&pt[d], accd[reg]);
                }
            }
        }

        // recurrence tile Mt = wid
        const f32x4 acc = __builtin_amdgcn_mfma_f32_16x16x32_bf16(
            afrag, bfrag, zero4, 0, 0, 0);
        // acc = {-z_i, -z_f, 2*z_g, -z_o} * log2e  (bias via k=30)
        const float iv = rcpf(1.0f + exp2fast(acc[0]));
        const float fv = rcpf(1.0f + exp2fast(acc[1]));
        const float gv = fmaf(-2.0f, rcpf(exp2fast(acc[2]) + 1.0f), 1.0f);
        const float ov = rcpf(1.0f + exp2fast(acc[3]));
        cst = fmaf(fv, cst, iv * gv);
        const float th = fmaf(-2.0f, rcpf(exp2fast(TLOG2E * cst) + 1.0f), 1.0f);
        const float hv = ov * th;

        // h(t): one bf16 store at k = g4*6 + wid into the other buffer
        bcol[p ^ 1][c16][g4 * 6 + wid] = (short)f2bf(hv);

        // wave0: stage x(t+1) int4 into the other buffer; prefetch x(t+2)
        if (wid == 0 && l < 16) {
            *(int4*)&bcol[p ^ 1][c16][KX] = xn4;
            const int tc = (t + 2 < T) ? t + 2 : T - 1;
            xn4 = xq[(size_t)tc * BPAD];
        }

        block_sync_lds();      // LDS-only barrier: atomics/loads stay in flight
        p ^= 1;
    }

    // final dense: buf[p] holds h(T-1)
    if (wid == 1) {
        const bf16x8 bfrag = *(const bf16x8*)&bcol[p][c16][8 * g4];
        const f32x4 accd = __builtin_amdgcn_mfma_f32_16x16x32_bf16(
            afrag_d, bfrag, zero4, 0, 0, 0);
        if (bvalid) {
            float* pt = ob + (size_t)(T - 1) * D;
            #pragma unroll
            for (int reg = 0; reg < 4; ++reg) {
                const int d = g4 * 4 + reg;
                if (d < D) atomicAdd(&pt[d], accd[reg]);
            }
        }
    }
}

extern "C" void kernel_launch(void* const* d_in, const int* in_sizes, int n_in,
                              void* d_out, int out_size, void* d_ws, size_t ws_size,
                              hipStream_t stream) {
    const float* x   = (const float*)d_in[0];
    const float* Wg  = (const float*)d_in[1];
    const float* Ug  = (const float*)d_in[2];
    const float* bg  = (const float*)d_in[3];
    const float* dWg = (const float*)d_in[4];
    const float* dbv = (const float*)d_in[5];
    float* out = (float*)d_out;

    // out = dense_b broadcast; lstm kernel accumulates dense partials on top.
    init_out_kernel<<<(out_size + 255) / 256, 256, 0, stream>>>(dbv, out, out_size);

    int4* xe = (int4*)d_ws;                   // T*BPAD*16B = 458,752 bytes
    xpack_kernel<<<(T * BPAD + 255) / 256, 256, 0, stream>>>(x, xe);

    lstm_mfma5_kernel<<<NL * NW, BLKT, 0, stream>>>(xe, Wg, Ug, bg, dWg, out);
}

// Round 18
// 219.877 us; speedup vs baseline: 7.6317x; 7.6317x over previous
//
#include <hip/hip_runtime.h>
#include <math.h>

// Problem constants: N=200 LSTMs, B=100, T=256, D=5 (io), H=20 (units)
constexpr int NL = 200;
constexpr int B  = 100;
constexpr int T  = 256;
constexpr int D  = 5;
constexpr int H  = 20;
constexpr int NW = 7;       // 16-batch groups per LSTM; 7*16=112 >= 100
constexpr int KP = 40;      // bcol row pitch in bf16 (80 B)
constexpr int NWAVE = 5;    // wave m computes recurrence tile Mt=m
constexpr int BLKT  = 64 * NWAVE;   // 320 threads
constexpr int BPAD  = 112;  // padded batch dim of xe

// k-axis layout of the per-batch data column (K=32):
//   k 0..23  = h region, k = g*6 + mt  (hh = mt*4 + g; mt==5 -> always 0)
//   k 24..28 = x_t[0..4]  (one int4 = 16B store per step, k24..31, via xpack)
//   k 30     = 1.0 (bias slot, baked into xpack), k 29,31 = 0
constexpr int KX = 24;

typedef float  f32x4  __attribute__((ext_vector_type(4)));
typedef short  bf16x8 __attribute__((ext_vector_type(8)));

__device__ __forceinline__ float rcpf(float x) { return __builtin_amdgcn_rcpf(x); }

#if __has_builtin(__builtin_amdgcn_exp2f)
__device__ __forceinline__ float exp2fast(float x) { return __builtin_amdgcn_exp2f(x); }
#else
__device__ __forceinline__ float exp2fast(float x) { return __expf(x * 0.6931471805599453f); }
#endif

// fp32 -> bf16 bits, round-to-nearest-even
__device__ __forceinline__ unsigned short f2bf(float f) {
    union { float f; unsigned u; } v; v.f = f;
    unsigned r = v.u + 0x7fffu + ((v.u >> 16) & 1u);
    return (unsigned short)(r >> 16);
}
__device__ __forceinline__ unsigned pk2bf(float lo, float hi) {
    return (unsigned)f2bf(lo) | ((unsigned)f2bf(hi) << 16);
}

// LDS-only block barrier: global stores (dense partials) and loads (x
// prefetch) stay in flight across steps (no vmcnt drain).
__device__ __forceinline__ void block_sync_lds() {
    asm volatile("s_waitcnt lgkmcnt(0)" ::: "memory");
    __builtin_amdgcn_s_barrier();
}

constexpr float NLOG2E = -1.4426950408889634f;
constexpr float TLOG2E = 2.8853900817779268f;   // 2*log2(e)

__global__ __launch_bounds__(256) void init_out_kernel(const float* __restrict__ dense_b,
                                                       float* __restrict__ out, int n) {
    int i = blockIdx.x * 256 + threadIdx.x;
    if (i < n) out[i] = dense_b[i % D];
}

// xe[t][b] = int4 B-fragment piece for k=24..31:
//   {pk(x0,x1), pk(x2,x3), pk(x4,0), pk(1.0,0)}  ([t][b] order -> 16
//   consecutive-b lanes read 256B = 2 cache lines)
__global__ __launch_bounds__(256) void xpack_kernel(const float* __restrict__ x,
                                                    int4* __restrict__ xe) {
    int i = blockIdx.x * 256 + threadIdx.x;   // i = t*BPAD + b
    if (i >= T * BPAD) return;
    const int t = i / BPAD;
    const int b = i % BPAD;
    int4 v = {0, 0, 0, 0};
    if (b < B) {
        const float* s = x + ((size_t)b * T + t) * D;
        v.x = (int)pk2bf(s[0], s[1]);
        v.y = (int)pk2bf(s[2], s[3]);
        v.z = (int)pk2bf(s[4], 0.0f);
        v.w = 0x00003F80;                     // (bf16 1.0, 0) -> k30 bias
    }
    xe[i] = v;
}

// One block per (lstm n, 16-batch group w); 5 waves per block (R10 structure,
// best measured: 230us). Wave m: ONE gate-tile MFMA + ONE activation chain
// per step; lane (c16,g4) owns (hh = 4m+g4, b = 16w+c16), writes ONE bf16 h.
// Wave 1 extra: dense MFMA, pipelined one step behind, written to the pw
// workspace (private slots, no atomics). Wave 0 lanes<16 extra: stage the
// pre-packed x int4 (1 load + 1 ds_write_b128 per step — slimmer straggler
// than R10's 5-cvt pack). bcol double-buffered; ONE lgkm-only barrier/step.
template<bool USE_WS>
__global__ __attribute__((amdgpu_flat_work_group_size(BLKT, BLKT)))
void lstm_mfma5_kernel(
    const int4*  __restrict__ xe,   // [T][BPAD] packed x fragments
    const float* __restrict__ Wg,   // [N][D][4H]
    const float* __restrict__ Ug,   // [N][H][4H]
    const float* __restrict__ bg,   // [N][4H]
    const float* __restrict__ dWg,  // [N*H][D]
    float* __restrict__ pw,         // [N][T][D][B] partials (USE_WS)
    float* __restrict__ out)        // [B][T][D] (atomic fallback)
{
    const int blk = blockIdx.x;            // 0..1399
    const int n   = blk / NW;
    const int w   = blk % NW;
    const int tid = threadIdx.x;
    const int wid = tid >> 6;              // 0..4 = Mt of this wave
    const int l   = tid & 63;
    const int c16 = l & 15;
    const int g4  = l >> 4;

    __shared__ __align__(16) short bcol[2][16][KP];   // double-buffered

    for (int i = tid; i < 2 * 16 * KP / 2; i += BLKT)
        ((int*)&bcol[0][0][0])[i] = 0;

    const float* Un = Ug  + (size_t)n * H * 4 * H;
    const float* Wn = Wg  + (size_t)n * D * 4 * H;
    const float* bn = bg  + (size_t)n * 4 * H;
    const float* dn = dWg + (size_t)n * H * D;

    // ---- recurrence A fragment for this wave (Mt = wid), k = 8*g4 + j ----
    const int gateA = c16 & 3;
    const int hA4   = c16 >> 2;
    const float sA  = (gateA == 2) ? TLOG2E : NLOG2E;
    const int colA  = gateA * H + (wid * 4 + hA4);   // column in [*,4H] weights
    bf16x8 afrag;
    #pragma unroll
    for (int j = 0; j < 8; ++j) {
        const int k = 8 * g4 + j;
        float v = 0.0f;
        if (k < KX) {                          // h region: k = g*6 + mt
            const int mt = k % 6, gg = k / 6;
            if (mt < 5) v = Un[(mt * 4 + gg) * 4 * H + colA];
        } else if (k < KX + D) {               // x region
            v = Wn[(k - KX) * 4 * H + colA];
        } else if (k == 30) {                  // bias slot
            v = bn[colA];
        }
        afrag[j] = (short)f2bf(sA * v);
    }
    // ---- dense A fragment (wave 1 only): rows 0..4 = d, h region only ----
    bf16x8 afrag_d = {};
    if (wid == 1) {
        #pragma unroll
        for (int j = 0; j < 8; ++j) {
            const int k = 8 * g4 + j;
            float v = 0.0f;
            if (c16 < D && k < KX) {
                const int mt = k % 6, gg = k / 6;
                if (mt < 5) v = dn[(mt * 4 + gg) * D + c16];
            }
            afrag_d[j] = (short)f2bf(v);
        }
    }

    const int  bgl    = w * 16 + c16;          // global batch of this lane-col
    const bool bvalid = bgl < B;
    const int4* xq = xe + bgl;                 // row stride BPAD
    float* pwn = USE_WS ? (pw + (size_t)n * T * (D * B))
                        : (out + ((size_t)bgl * T) * D);

    __syncthreads();                            // zero-init visible

    // prologue: wave0 stages x(0) into buf 0; preloads x(1)
    int4 xn4;
    if (wid == 0 && l < 16) {
        *(int4*)&bcol[0][c16][KX] = xq[0];
        xn4 = xq[(T > 1 ? 1 : 0) * BPAD];
    }
    __syncthreads();

    float cst = 0.0f;
    const f32x4 zero4 = {0.0f, 0.0f, 0.0f, 0.0f};
    int p = 0;

    for (int t = 0; t < T; ++t) {
        // buf[p] holds h(t-1) and x(t)
        const bf16x8 bfrag = *(const bf16x8*)&bcol[p][c16][8 * g4];  // ds_read_b128

        if (wid == 1) {
            // dense for step t-1 (uses h(t-1) in bfrag)
            const f32x4 accd = __builtin_amdgcn_mfma_f32_16x16x32_bf16(
                afrag_d, bfrag, zero4, 0, 0, 0);
            if (t > 0 && bvalid) {
                #pragma unroll
                for (int reg = 0; reg < 4; ++reg) {
                    const int d = g4 * 4 + reg;            // output row = d
                    if (d < D) {
                        if (USE_WS)
                            pwn[(size_t)(t - 1) * (D * B) + d * B + bgl] = accd[reg];
                        else
                            atomicAdd(&pwn[(size_t)(t - 1) * D + d], accd[reg]);
                    }
                }
            }
        }

        // recurrence tile Mt = wid
        const f32x4 acc = __builtin_amdgcn_mfma_f32_16x16x32_bf16(
            afrag, bfrag, zero4, 0, 0, 0);
        // acc = {-z_i, -z_f, 2*z_g, -z_o} * log2e  (bias via k=30)
        const float iv = rcpf(1.0f + exp2fast(acc[0]));
        const float fv = rcpf(1.0f + exp2fast(acc[1]));
        const float gv = fmaf(-2.0f, rcpf(exp2fast(acc[2]) + 1.0f), 1.0f);
        const float ov = rcpf(1.0f + exp2fast(acc[3]));
        cst = fmaf(fv, cst, iv * gv);
        const float th = fmaf(-2.0f, rcpf(exp2fast(TLOG2E * cst) + 1.0f), 1.0f);
        const float hv = ov * th;

        // h(t): one bf16 store at k = g4*6 + wid into the other buffer
        bcol[p ^ 1][c16][g4 * 6 + wid] = (short)f2bf(hv);

        // wave0: stage x(t+1) int4 into the other buffer; prefetch x(t+2)
        if (wid == 0 && l < 16) {
            *(int4*)&bcol[p ^ 1][c16][KX] = xn4;
            const int tc = (t + 2 < T) ? t + 2 : T - 1;
            xn4 = xq[(size_t)tc * BPAD];
        }

        block_sync_lds();      // LDS-only barrier: stores/loads stay in flight
        p ^= 1;
    }

    // final dense: buf[p] holds h(T-1)
    if (wid == 1) {
        const bf16x8 bfrag = *(const bf16x8*)&bcol[p][c16][8 * g4];
        const f32x4 accd = __builtin_amdgcn_mfma_f32_16x16x32_bf16(
            afrag_d, bfrag, zero4, 0, 0, 0);
        if (bvalid) {
            #pragma unroll
            for (int reg = 0; reg < 4; ++reg) {
                const int d = g4 * 4 + reg;
                if (d < D) {
                    if (USE_WS)
                        pwn[(size_t)(T - 1) * (D * B) + d * B + bgl] = accd[reg];
                    else
                        atomicAdd(&pwn[(size_t)(T - 1) * D + d], accd[reg]);
                }
            }
        }
    }
}

// out[b][t][d] = dense_b[d] + sum_n pw[n][t][d][b]  (coalesced reads)
__global__ __launch_bounds__(512) void reduce_kernel(
    const float* __restrict__ pw, const float* __restrict__ dense_b,
    float* __restrict__ out)
{
    const int t    = blockIdx.x;
    const int flat = threadIdx.x;              // d*B + b, 0..499
    if (flat >= B * D) return;
    const int d = flat / B;
    const int b = flat % B;
    const float* p = pw + (size_t)t * (D * B) + flat;
    constexpr size_t stride = (size_t)T * D * B;
    float a0 = 0.0f, a1 = 0.0f;
    #pragma unroll 10
    for (int n = 0; n < NL; n += 2) {
        a0 += p[(size_t)n * stride];
        a1 += p[(size_t)(n + 1) * stride];
    }
    out[((size_t)b * T + t) * D + d] = a0 + a1 + dense_b[d];
}

extern "C" void kernel_launch(void* const* d_in, const int* in_sizes, int n_in,
                              void* d_out, int out_size, void* d_ws, size_t ws_size,
                              hipStream_t stream) {
    const float* x   = (const float*)d_in[0];
    const float* Wg  = (const float*)d_in[1];
    const float* Ug  = (const float*)d_in[2];
    const float* bg  = (const float*)d_in[3];
    const float* dWg = (const float*)d_in[4];
    const float* dbv = (const float*)d_in[5];
    float* out = (float*)d_out;

    const size_t xe_bytes = (size_t)T * BPAD * sizeof(int4);          // 458,752
    const size_t pw_bytes = (size_t)NL * T * D * B * sizeof(float);   // 102.4 MB

    int4* xe = (int4*)d_ws;
    xpack_kernel<<<(T * BPAD + 255) / 256, 256, 0, stream>>>(x, xe);

    if (ws_size >= xe_bytes + pw_bytes) {
        float* pw = (float*)((char*)d_ws + xe_bytes);
        lstm_mfma5_kernel<true><<<NL * NW, BLKT, 0, stream>>>(xe, Wg, Ug, bg, dWg, pw, out);
        reduce_kernel<<<T, 512, 0, stream>>>(pw, dbv, out);
    } else {
        init_out_kernel<<<(out_size + 255) / 256, 256, 0, stream>>>(dbv, out, out_size);
        lstm_mfma5_kernel<false><<<NL * NW, BLKT, 0, stream>>>(xe, Wg, Ug, bg, dWg, nullptr, out);
    }
}

// Round 19
// 215.478 us; speedup vs baseline: 7.7875x; 1.0204x over previous
//
#include <hip/hip_runtime.h>
#include <math.h>

// Problem constants: N=200 LSTMs, B=100, T=256, D=5 (io), H=20 (units)
constexpr int NL = 200;
constexpr int B  = 100;
constexpr int T  = 256;
constexpr int D  = 5;
constexpr int H  = 20;
constexpr int NW = 7;        // 16-batch groups per LSTM; 7*16=112 >= 100
constexpr int KP = 40;       // bcol row pitch in bf16 (80 B)
constexpr int NWAVE = 5;     // wave m computes recurrence tile Mt=m (both jobs)
constexpr int BLKT  = 64 * NWAVE;   // 320 threads
constexpr int BPAD  = 112;   // padded batch dim of xe
constexpr int NPAIR = NL / 2;       // block runs jobs (pr, pr+100)

// k-axis layout of the per-batch data column (K=32):
//   k 0..23  = h region, k = g*6 + mt  (hh = mt*4 + g; mt==5 -> always 0)
//   k 24..28 = x_t[0..4]  (one int4 = 16B store per step, k24..31, via xpack)
//   k 30     = 1.0 (bias slot, baked into xpack), k 29,31 = 0
constexpr int KX = 24;

typedef float  f32x4  __attribute__((ext_vector_type(4)));
typedef short  bf16x8 __attribute__((ext_vector_type(8)));

__device__ __forceinline__ float rcpf(float x) { return __builtin_amdgcn_rcpf(x); }

#if __has_builtin(__builtin_amdgcn_exp2f)
__device__ __forceinline__ float exp2fast(float x) { return __builtin_amdgcn_exp2f(x); }
#else
__device__ __forceinline__ float exp2fast(float x) { return __expf(x * 0.6931471805599453f); }
#endif

// fp32 -> bf16 bits, round-to-nearest-even
__device__ __forceinline__ unsigned short f2bf(float f) {
    union { float f; unsigned u; } v; v.f = f;
    unsigned r = v.u + 0x7fffu + ((v.u >> 16) & 1u);
    return (unsigned short)(r >> 16);
}
__device__ __forceinline__ unsigned pk2bf(float lo, float hi) {
    return (unsigned)f2bf(lo) | ((unsigned)f2bf(hi) << 16);
}

// LDS-only block barrier: global stores (dense partials) and loads (x
// prefetch) stay in flight across steps (no vmcnt drain).
__device__ __forceinline__ void block_sync_lds() {
    asm volatile("s_waitcnt lgkmcnt(0)" ::: "memory");
    __builtin_amdgcn_s_barrier();
}

constexpr float NLOG2E = -1.4426950408889634f;
constexpr float TLOG2E = 2.8853900817779268f;   // 2*log2(e)

__global__ __launch_bounds__(256) void init_out_kernel(const float* __restrict__ dense_b,
                                                       float* __restrict__ out, int n) {
    int i = blockIdx.x * 256 + threadIdx.x;
    if (i < n) out[i] = dense_b[i % D];
}

// xe[t][b] = int4 B-fragment piece for k=24..31:
//   {pk(x0,x1), pk(x2,x3), pk(x4,0), pk(1.0,0)}
__global__ __launch_bounds__(256) void xpack_kernel(const float* __restrict__ x,
                                                    int4* __restrict__ xe) {
    int i = blockIdx.x * 256 + threadIdx.x;   // i = t*BPAD + b
    if (i >= T * BPAD) return;
    const int t = i / BPAD;
    const int b = i % BPAD;
    int4 v = {0, 0, 0, 0};
    if (b < B) {
        const float* s = x + ((size_t)b * T + t) * D;
        v.x = (int)pk2bf(s[0], s[1]);
        v.y = (int)pk2bf(s[2], s[3]);
        v.z = (int)pk2bf(s[4], 0.0f);
        v.w = 0x00003F80;                     // (bf16 1.0, 0) -> k30 bias
    }
    xe[i] = v;
}

__device__ __forceinline__ float lstm_act(const f32x4 a, float& c) {
    // a = {-z_i, -z_f, 2*z_g, -z_o} * log2e (bias folded into MFMA A)
    const float iv = rcpf(1.0f + exp2fast(a[0]));
    const float fv = rcpf(1.0f + exp2fast(a[1]));
    const float gv = fmaf(-2.0f, rcpf(exp2fast(a[2]) + 1.0f), 1.0f);
    const float ov = rcpf(1.0f + exp2fast(a[3]));
    c = fmaf(fv, c, iv * gv);
    const float th = fmaf(-2.0f, rcpf(exp2fast(TLOG2E * c) + 1.0f), 1.0f);
    return ov * th;
}

// One block per (pair pr, 16-batch group w) running TWO LSTMs (n0=pr,
// n1=pr+100) in lockstep — the barrier is amortized over 2x work and the two
// jobs' independent MFMA->act chains interleave in each wave's issue stream.
// Wave m: gate tile Mt=m for BOTH jobs + 2 act chains + 2 bf16 h writes.
// Wave 1 extra: dense MFMA job0; wave 2 extra: dense MFMA job1 (split
// stragglers). Wave 0 lanes<16: one shared x int4 load -> both jobs' bufs.
// bcol double-buffered per job; ONE lgkm-only barrier per step.
template<bool USE_WS>
__global__ __attribute__((amdgpu_flat_work_group_size(BLKT, BLKT)))
void lstm_mfma5x2_kernel(
    const int4*  __restrict__ xe,   // [T][BPAD] packed x fragments
    const float* __restrict__ Wg,   // [N][D][4H]
    const float* __restrict__ Ug,   // [N][H][4H]
    const float* __restrict__ bg,   // [N][4H]
    const float* __restrict__ dWg,  // [N*H][D]
    float* __restrict__ pw,         // [N][T][D][B] partials (USE_WS)
    float* __restrict__ out)        // [B][T][D] (atomic fallback)
{
    const int blk = blockIdx.x;            // 0..699
    const int pr  = blk / NW;
    const int w   = blk % NW;
    const int n0  = pr;
    const int n1  = pr + NPAIR;
    const int tid = threadIdx.x;
    const int wid = tid >> 6;              // 0..4 = Mt of this wave
    const int l   = tid & 63;
    const int c16 = l & 15;
    const int g4  = l >> 4;

    __shared__ __align__(16) short bcol[2][2][16][KP];   // [job][buf][b][k], 5 KB

    for (int i = tid; i < 2 * 2 * 16 * KP / 2; i += BLKT)
        ((int*)&bcol[0][0][0][0])[i] = 0;

    // ---- A fragments (both jobs), element j <-> k = 8*g4 + j ----
    const int gateA = c16 & 3;
    const int hA4   = c16 >> 2;
    const float sA  = (gateA == 2) ? TLOG2E : NLOG2E;
    auto buildA = [&](int n) {
        const float* Un = Ug + (size_t)n * H * 4 * H;
        const float* Wn = Wg + (size_t)n * D * 4 * H;
        const float* bn = bg + (size_t)n * 4 * H;
        const int colA  = gateA * H + (wid * 4 + hA4);
        bf16x8 a;
        #pragma unroll
        for (int j = 0; j < 8; ++j) {
            const int k = 8 * g4 + j;
            float v = 0.0f;
            if (k < KX) {                      // h region: k = g*6 + mt
                const int mt = k % 6, gg = k / 6;
                if (mt < 5) v = Un[(mt * 4 + gg) * 4 * H + colA];
            } else if (k < KX + D) {           // x region
                v = Wn[(k - KX) * 4 * H + colA];
            } else if (k == 30) {              // bias slot
                v = bn[colA];
            }
            a[j] = (short)f2bf(sA * v);
        }
        return a;
    };
    auto buildD = [&](int n) {
        const float* dn = dWg + (size_t)n * H * D;
        bf16x8 a;
        #pragma unroll
        for (int j = 0; j < 8; ++j) {
            const int k = 8 * g4 + j;
            float v = 0.0f;
            if (c16 < D && k < KX) {
                const int mt = k % 6, gg = k / 6;
                if (mt < 5) v = dn[(mt * 4 + gg) * D + c16];
            }
            a[j] = (short)f2bf(v);
        }
        return a;
    };
    const bf16x8 af0 = buildA(n0);
    const bf16x8 af1 = buildA(n1);
    bf16x8 afd = {};
    if (wid == 1) afd = buildD(n0);            // wave1 owns dense of job0
    if (wid == 2) afd = buildD(n1);            // wave2 owns dense of job1

    const int  bgl    = w * 16 + c16;          // global batch of this lane-col
    const bool bvalid = bgl < B;
    const int4* xq = xe + bgl;                 // row stride BPAD
    const int   dn_  = (wid == 2) ? n1 : n0;   // dense job of this wave
    float* pwn = USE_WS ? (pw + (size_t)dn_ * T * (D * B))
                        : (out + ((size_t)bgl * T) * D);

    __syncthreads();                            // zero-init visible

    // prologue: wave0 stages x(0) into both jobs' buf 0; preloads x(1)
    int4 xn4;
    if (wid == 0 && l < 16) {
        const int4 x0 = xq[0];
        *(int4*)&bcol[0][0][c16][KX] = x0;
        *(int4*)&bcol[1][0][c16][KX] = x0;
        xn4 = xq[(T > 1 ? 1 : 0) * BPAD];
    }
    __syncthreads();

    float cst0 = 0.0f, cst1 = 0.0f;
    const f32x4 zero4 = {0.0f, 0.0f, 0.0f, 0.0f};
    int p = 0;

    for (int t = 0; t < T; ++t) {
        // buf[p] holds h(t-1) and x(t) for both jobs
        const bf16x8 bf0 = *(const bf16x8*)&bcol[0][p][c16][8 * g4];
        const bf16x8 bf1 = *(const bf16x8*)&bcol[1][p][c16][8 * g4];

        // dense for step t-1: wave1 -> job0, wave2 -> job1
        if (wid == 1 || wid == 2) {
            const bf16x8 bfd = (wid == 1) ? bf0 : bf1;
            const f32x4 accd = __builtin_amdgcn_mfma_f32_16x16x32_bf16(
                afd, bfd, zero4, 0, 0, 0);
            if (t > 0 && bvalid) {
                #pragma unroll
                for (int reg = 0; reg < 4; ++reg) {
                    const int d = g4 * 4 + reg;            // output row = d
                    if (d < D) {
                        if (USE_WS)
                            pwn[(size_t)(t - 1) * (D * B) + d * B + bgl] = accd[reg];
                        else
                            atomicAdd(&pwn[(size_t)(t - 1) * D + d], accd[reg]);
                    }
                }
            }
        }

        // recurrence tile Mt = wid, both jobs (independent chains -> ILP)
        const f32x4 a0 = __builtin_amdgcn_mfma_f32_16x16x32_bf16(af0, bf0, zero4, 0, 0, 0);
        const f32x4 a1 = __builtin_amdgcn_mfma_f32_16x16x32_bf16(af1, bf1, zero4, 0, 0, 0);
        const float h0 = lstm_act(a0, cst0);
        const float h1 = lstm_act(a1, cst1);

        // h(t): one bf16 store per job at k = g4*6 + wid into the other buffer
        bcol[0][p ^ 1][c16][g4 * 6 + wid] = (short)f2bf(h0);
        bcol[1][p ^ 1][c16][g4 * 6 + wid] = (short)f2bf(h1);

        // wave0: stage x(t+1) into both jobs' other buffer; prefetch x(t+2)
        if (wid == 0 && l < 16) {
            *(int4*)&bcol[0][p ^ 1][c16][KX] = xn4;
            *(int4*)&bcol[1][p ^ 1][c16][KX] = xn4;
            const int tc = (t + 2 < T) ? t + 2 : T - 1;
            xn4 = xq[(size_t)tc * BPAD];
        }

        block_sync_lds();      // LDS-only barrier: stores/loads stay in flight
        p ^= 1;
    }

    // final dense: buf[p] holds h(T-1)
    if (wid == 1 || wid == 2) {
        const bf16x8 bfd = *(const bf16x8*)&bcol[wid - 1][p][c16][8 * g4];
        const f32x4 accd = __builtin_amdgcn_mfma_f32_16x16x32_bf16(
            afd, bfd, zero4, 0, 0, 0);
        if (bvalid) {
            #pragma unroll
            for (int reg = 0; reg < 4; ++reg) {
                const int d = g4 * 4 + reg;
                if (d < D) {
                    if (USE_WS)
                        pwn[(size_t)(T - 1) * (D * B) + d * B + bgl] = accd[reg];
                    else
                        atomicAdd(&pwn[(size_t)(T - 1) * D + d], accd[reg]);
                }
            }
        }
    }
}

// out[b][t][d] = dense_b[d] + sum_n pw[n][t][d][b]  (coalesced reads)
__global__ __launch_bounds__(512) void reduce_kernel(
    const float* __restrict__ pw, const float* __restrict__ dense_b,
    float* __restrict__ out)
{
    const int t    = blockIdx.x;
    const int flat = threadIdx.x;              // d*B + b, 0..499
    if (flat >= B * D) return;
    const int d = flat / B;
    const int b = flat % B;
    const float* p = pw + (size_t)t * (D * B) + flat;
    constexpr size_t stride = (size_t)T * D * B;
    float a0 = 0.0f, a1 = 0.0f;
    #pragma unroll 10
    for (int n = 0; n < NL; n += 2) {
        a0 += p[(size_t)n * stride];
        a1 += p[(size_t)(n + 1) * stride];
    }
    out[((size_t)b * T + t) * D + d] = a0 + a1 + dense_b[d];
}

extern "C" void kernel_launch(void* const* d_in, const int* in_sizes, int n_in,
                              void* d_out, int out_size, void* d_ws, size_t ws_size,
                              hipStream_t stream) {
    const float* x   = (const float*)d_in[0];
    const float* Wg  = (const float*)d_in[1];
    const float* Ug  = (const float*)d_in[2];
    const float* bg  = (const float*)d_in[3];
    const float* dWg = (const float*)d_in[4];
    const float* dbv = (const float*)d_in[5];
    float* out = (float*)d_out;

    const size_t xe_bytes = (size_t)T * BPAD * sizeof(int4);          // 458,752
    const size_t pw_bytes = (size_t)NL * T * D * B * sizeof(float);   // 102.4 MB

    int4* xe = (int4*)d_ws;
    xpack_kernel<<<(T * BPAD + 255) / 256, 256, 0, stream>>>(x, xe);

    if (ws_size >= xe_bytes + pw_bytes) {
        float* pw = (float*)((char*)d_ws + xe_bytes);
        lstm_mfma5x2_kernel<true><<<NPAIR * NW, BLKT, 0, stream>>>(xe, Wg, Ug, bg, dWg, pw, out);
        reduce_kernel<<<T, 512, 0, stream>>>(pw, dbv, out);
    } else {
        init_out_kernel<<<(out_size + 255) / 256, 256, 0, stream>>>(dbv, out, out_size);
        lstm_mfma5x2_kernel<false><<<NPAIR * NW, BLKT, 0, stream>>>(xe, Wg, Ug, bg, dWg, nullptr, out);
    }
}

// Round 20
// 198.303 us; speedup vs baseline: 8.4619x; 1.0866x over previous
//
#include <hip/hip_runtime.h>
#include <math.h>

// Problem constants: N=200 LSTMs, B=100, T=256, D=5 (io), H=20 (units)
constexpr int NL = 200;
constexpr int B  = 100;
constexpr int T  = 256;
constexpr int D  = 5;
constexpr int H  = 20;
constexpr int NW = 7;        // 16-batch groups per LSTM; 7*16=112 >= 100
constexpr int KP = 40;       // bcol row pitch in bf16 (80 B)
constexpr int NWAVE = 5;     // wave m computes recurrence tile Mt=m (both jobs)
constexpr int BLKT  = 64 * NWAVE;   // 320 threads
constexpr int BPAD  = 112;   // padded batch dim of xe
constexpr int NPAIR = NL / 2;       // block runs jobs (pr, pr+100)

// k-axis layout of the per-batch data column (K=32):
//   k 0..23  = h region, k = g*6 + mt  (hh = mt*4 + g; mt==5 -> always 0)
//   k 24..28 = x_t[0..4]  (one int4 = 16B store per step, k24..31, via xpack)
//   k 30     = 1.0 (bias slot, baked into xpack), k 29,31 = 0
constexpr int KX = 24;

typedef float  f32x4  __attribute__((ext_vector_type(4)));
typedef short  bf16x8 __attribute__((ext_vector_type(8)));

__device__ __forceinline__ float rcpf(float x) { return __builtin_amdgcn_rcpf(x); }

#if __has_builtin(__builtin_amdgcn_exp2f)
__device__ __forceinline__ float exp2fast(float x) { return __builtin_amdgcn_exp2f(x); }
#else
__device__ __forceinline__ float exp2fast(float x) { return __expf(x * 0.6931471805599453f); }
#endif

// fp32 -> bf16 bits, round-to-nearest-even
__device__ __forceinline__ unsigned short f2bf(float f) {
    union { float f; unsigned u; } v; v.f = f;
    unsigned r = v.u + 0x7fffu + ((v.u >> 16) & 1u);
    return (unsigned short)(r >> 16);
}
__device__ __forceinline__ unsigned pk2bf(float lo, float hi) {
    return (unsigned)f2bf(lo) | ((unsigned)f2bf(hi) << 16);
}

// LDS-only block barrier: global stores (dense partials) and loads (x
// prefetch) stay in flight across steps (no vmcnt drain).
__device__ __forceinline__ void block_sync_lds() {
    asm volatile("s_waitcnt lgkmcnt(0)" ::: "memory");
    __builtin_amdgcn_s_barrier();
}

constexpr float NLOG2E = -1.4426950408889634f;
constexpr float TLOG2E = 2.8853900817779268f;   // 2*log2(e)

__global__ __launch_bounds__(256) void init_out_kernel(const float* __restrict__ dense_b,
                                                       float* __restrict__ out, int n) {
    int i = blockIdx.x * 256 + threadIdx.x;
    if (i < n) out[i] = dense_b[i % D];
}

// xe[t][b] = int4 B-fragment piece for k=24..31:
//   {pk(x0,x1), pk(x2,x3), pk(x4,0), pk(1.0,0)}
__global__ __launch_bounds__(256) void xpack_kernel(const float* __restrict__ x,
                                                    int4* __restrict__ xe) {
    int i = blockIdx.x * 256 + threadIdx.x;   // i = t*BPAD + b
    if (i >= T * BPAD) return;
    const int t = i / BPAD;
    const int b = i % BPAD;
    int4 v = {0, 0, 0, 0};
    if (b < B) {
        const float* s = x + ((size_t)b * T + t) * D;
        v.x = (int)pk2bf(s[0], s[1]);
        v.y = (int)pk2bf(s[2], s[3]);
        v.z = (int)pk2bf(s[4], 0.0f);
        v.w = 0x00003F80;                     // (bf16 1.0, 0) -> k30 bias
    }
    xe[i] = v;
}

__device__ __forceinline__ float lstm_act(const f32x4 a, float& c) {
    // a = {-z_i, -z_f, 2*z_g, -z_o} * log2e (bias folded into MFMA A)
    const float iv = rcpf(1.0f + exp2fast(a[0]));
    const float fv = rcpf(1.0f + exp2fast(a[1]));
    const float gv = fmaf(-2.0f, rcpf(exp2fast(a[2]) + 1.0f), 1.0f);
    const float ov = rcpf(1.0f + exp2fast(a[3]));
    c = fmaf(fv, c, iv * gv);
    const float th = fmaf(-2.0f, rcpf(exp2fast(TLOG2E * c) + 1.0f), 1.0f);
    return ov * th;
}

// One block per (pair pr, 16-batch group w) running TWO LSTMs (n0=pr,
// n1=pr+100) in lockstep. Wave m: gate tile Mt=m for BOTH jobs + 2 act
// chains + 2 bf16 h writes. Wave 1 extra: PAIR-SUMMED dense via MFMA
// C-chaining — mfma(afd1, bf1, mfma(afd0, bf0, 0)) — one store set, pw
// halved to [NPAIR][T][D][B] (halves reduce-pass HBM traffic). Wave 0
// lanes<16: one shared x int4 load -> both jobs' bufs. bcol double-buffered
// per job; ONE lgkm-only barrier per step.
template<bool USE_WS>
__global__ __attribute__((amdgpu_flat_work_group_size(BLKT, BLKT)))
void lstm_mfma5x2_kernel(
    const int4*  __restrict__ xe,   // [T][BPAD] packed x fragments
    const float* __restrict__ Wg,   // [N][D][4H]
    const float* __restrict__ Ug,   // [N][H][4H]
    const float* __restrict__ bg,   // [N][4H]
    const float* __restrict__ dWg,  // [N*H][D]
    float* __restrict__ pw,         // [NPAIR][T][D][B] pair-summed partials
    float* __restrict__ out)        // [B][T][D] (atomic fallback)
{
    const int blk = blockIdx.x;            // 0..699
    const int pr  = blk / NW;
    const int w   = blk % NW;
    const int n0  = pr;
    const int n1  = pr + NPAIR;
    const int tid = threadIdx.x;
    const int wid = tid >> 6;              // 0..4 = Mt of this wave
    const int l   = tid & 63;
    const int c16 = l & 15;
    const int g4  = l >> 4;

    __shared__ __align__(16) short bcol[2][2][16][KP];   // [job][buf][b][k], 5 KB

    for (int i = tid; i < 2 * 2 * 16 * KP / 2; i += BLKT)
        ((int*)&bcol[0][0][0][0])[i] = 0;

    // ---- A fragments (both jobs), element j <-> k = 8*g4 + j ----
    const int gateA = c16 & 3;
    const int hA4   = c16 >> 2;
    const float sA  = (gateA == 2) ? TLOG2E : NLOG2E;
    auto buildA = [&](int n) {
        const float* Un = Ug + (size_t)n * H * 4 * H;
        const float* Wn = Wg + (size_t)n * D * 4 * H;
        const float* bn = bg + (size_t)n * 4 * H;
        const int colA  = gateA * H + (wid * 4 + hA4);
        bf16x8 a;
        #pragma unroll
        for (int j = 0; j < 8; ++j) {
            const int k = 8 * g4 + j;
            float v = 0.0f;
            if (k < KX) {                      // h region: k = g*6 + mt
                const int mt = k % 6, gg = k / 6;
                if (mt < 5) v = Un[(mt * 4 + gg) * 4 * H + colA];
            } else if (k < KX + D) {           // x region
                v = Wn[(k - KX) * 4 * H + colA];
            } else if (k == 30) {              // bias slot
                v = bn[colA];
            }
            a[j] = (short)f2bf(sA * v);
        }
        return a;
    };
    auto buildD = [&](int n) {
        const float* dn = dWg + (size_t)n * H * D;
        bf16x8 a;
        #pragma unroll
        for (int j = 0; j < 8; ++j) {
            const int k = 8 * g4 + j;
            float v = 0.0f;
            if (c16 < D && k < KX) {
                const int mt = k % 6, gg = k / 6;
                if (mt < 5) v = dn[(mt * 4 + gg) * D + c16];
            }
            a[j] = (short)f2bf(v);
        }
        return a;
    };
    const bf16x8 af0 = buildA(n0);
    const bf16x8 af1 = buildA(n1);
    bf16x8 afd0 = {}, afd1 = {};
    if (wid == 1) { afd0 = buildD(n0); afd1 = buildD(n1); }   // wave1 owns dense (pair)

    const int  bgl    = w * 16 + c16;          // global batch of this lane-col
    const bool bvalid = bgl < B;
    const int4* xq = xe + bgl;                 // row stride BPAD
    float* pwn = USE_WS ? (pw + (size_t)pr * T * (D * B))
                        : (out + ((size_t)bgl * T) * D);

    __syncthreads();                            // zero-init visible

    // prologue: wave0 stages x(0) into both jobs' buf 0; preloads x(1)
    int4 xn4;
    if (wid == 0 && l < 16) {
        const int4 x0 = xq[0];
        *(int4*)&bcol[0][0][c16][KX] = x0;
        *(int4*)&bcol[1][0][c16][KX] = x0;
        xn4 = xq[(T > 1 ? 1 : 0) * BPAD];
    }
    __syncthreads();

    float cst0 = 0.0f, cst1 = 0.0f;
    const f32x4 zero4 = {0.0f, 0.0f, 0.0f, 0.0f};
    int p = 0;

    for (int t = 0; t < T; ++t) {
        // buf[p] holds h(t-1) and x(t) for both jobs
        const bf16x8 bf0 = *(const bf16x8*)&bcol[0][p][c16][8 * g4];
        const bf16x8 bf1 = *(const bf16x8*)&bcol[1][p][c16][8 * g4];

        // pair-summed dense for step t-1 (wave1 only): dense(n0)+dense(n1)
        // via C-chaining; x/bias rows of afd* are zero so x contributes 0.
        if (wid == 1) {
            const f32x4 acc0 = __builtin_amdgcn_mfma_f32_16x16x32_bf16(
                afd0, bf0, zero4, 0, 0, 0);
            const f32x4 accd = __builtin_amdgcn_mfma_f32_16x16x32_bf16(
                afd1, bf1, acc0, 0, 0, 0);
            if (t > 0 && bvalid) {
                #pragma unroll
                for (int reg = 0; reg < 4; ++reg) {
                    const int d = g4 * 4 + reg;            // output row = d
                    if (d < D) {
                        if (USE_WS)
                            pwn[(size_t)(t - 1) * (D * B) + d * B + bgl] = accd[reg];
                        else
                            atomicAdd(&pwn[(size_t)(t - 1) * D + d], accd[reg]);
                    }
                }
            }
        }

        // recurrence tile Mt = wid, both jobs (independent chains -> ILP)
        const f32x4 a0 = __builtin_amdgcn_mfma_f32_16x16x32_bf16(af0, bf0, zero4, 0, 0, 0);
        const f32x4 a1 = __builtin_amdgcn_mfma_f32_16x16x32_bf16(af1, bf1, zero4, 0, 0, 0);
        const float h0 = lstm_act(a0, cst0);
        const float h1 = lstm_act(a1, cst1);

        // h(t): one bf16 store per job at k = g4*6 + wid into the other buffer
        bcol[0][p ^ 1][c16][g4 * 6 + wid] = (short)f2bf(h0);
        bcol[1][p ^ 1][c16][g4 * 6 + wid] = (short)f2bf(h1);

        // wave0: stage x(t+1) into both jobs' other buffer; prefetch x(t+2)
        if (wid == 0 && l < 16) {
            *(int4*)&bcol[0][p ^ 1][c16][KX] = xn4;
            *(int4*)&bcol[1][p ^ 1][c16][KX] = xn4;
            const int tc = (t + 2 < T) ? t + 2 : T - 1;
            xn4 = xq[(size_t)tc * BPAD];
        }

        block_sync_lds();      // LDS-only barrier: stores/loads stay in flight
        p ^= 1;
    }

    // final dense: buf[p] holds h(T-1)
    if (wid == 1) {
        const bf16x8 bf0 = *(const bf16x8*)&bcol[0][p][c16][8 * g4];
        const bf16x8 bf1 = *(const bf16x8*)&bcol[1][p][c16][8 * g4];
        const f32x4 acc0 = __builtin_amdgcn_mfma_f32_16x16x32_bf16(
            afd0, bf0, zero4, 0, 0, 0);
        const f32x4 accd = __builtin_amdgcn_mfma_f32_16x16x32_bf16(
            afd1, bf1, acc0, 0, 0, 0);
        if (bvalid) {
            #pragma unroll
            for (int reg = 0; reg < 4; ++reg) {
                const int d = g4 * 4 + reg;
                if (d < D) {
                    if (USE_WS)
                        pwn[(size_t)(T - 1) * (D * B) + d * B + bgl] = accd[reg];
                    else
                        atomicAdd(&pwn[(size_t)(T - 1) * D + d], accd[reg]);
                }
            }
        }
    }
}

// out[b][t][d] = dense_b[d] + sum over NPAIR pair-sums of pw[pr][t][d][b]
__global__ __launch_bounds__(512) void reduce_kernel(
    const float* __restrict__ pw, const float* __restrict__ dense_b,
    float* __restrict__ out)
{
    const int t    = blockIdx.x;
    const int flat = threadIdx.x;              // d*B + b, 0..499
    if (flat >= B * D) return;
    const int d = flat / B;
    const int b = flat % B;
    const float* p = pw + (size_t)t * (D * B) + flat;
    constexpr size_t stride = (size_t)T * D * B;
    float a0 = 0.0f, a1 = 0.0f;
    #pragma unroll 10
    for (int n = 0; n < NPAIR; n += 2) {
        a0 += p[(size_t)n * stride];
        a1 += p[(size_t)(n + 1) * stride];
    }
    out[((size_t)b * T + t) * D + d] = a0 + a1 + dense_b[d];
}

extern "C" void kernel_launch(void* const* d_in, const int* in_sizes, int n_in,
                              void* d_out, int out_size, void* d_ws, size_t ws_size,
                              hipStream_t stream) {
    const float* x   = (const float*)d_in[0];
    const float* Wg  = (const float*)d_in[1];
    const float* Ug  = (const float*)d_in[2];
    const float* bg  = (const float*)d_in[3];
    const float* dWg = (const float*)d_in[4];
    const float* dbv = (const float*)d_in[5];
    float* out = (float*)d_out;

    const size_t xe_bytes = (size_t)T * BPAD * sizeof(int4);             // 458,752
    const size_t pw_bytes = (size_t)NPAIR * T * D * B * sizeof(float);   // 51.2 MB

    int4* xe = (int4*)d_ws;
    xpack_kernel<<<(T * BPAD + 255) / 256, 256, 0, stream>>>(x, xe);

    if (ws_size >= xe_bytes + pw_bytes) {
        float* pw = (float*)((char*)d_ws + xe_bytes);
        lstm_mfma5x2_kernel<true><<<NPAIR * NW, BLKT, 0, stream>>>(xe, Wg, Ug, bg, dWg, pw, out);
        reduce_kernel<<<T, 512, 0, stream>>>(pw, dbv, out);
    } else {
        init_out_kernel<<<(out_size + 255) / 256, 256, 0, stream>>>(dbv, out, out_size);
        lstm_mfma5x2_kernel<false><<<NPAIR * NW, BLKT, 0, stream>>>(xe, Wg, Ug, bg, dWg, nullptr, out);
    }
}